// Round 6
// baseline (335.845 us; speedup 1.0000x reference)
//
#include <hip/hip_runtime.h>
#include <hip/hip_bf16.h>

// Problem constants
constexpr int BB = 8192;   // batch rows
constexpr int CC = 2048;   // classes
constexpr int FF = 2048;   // features (K)

typedef __bf16 bf16x8 __attribute__((ext_vector_type(8)));
typedef float  f32x4  __attribute__((ext_vector_type(4)));

typedef __attribute__((address_space(1))) unsigned int gu32;
typedef __attribute__((address_space(3))) unsigned int lu32;

// async global->LDS, 16B per lane. LDS side is wave-uniform base + lane*16.
__device__ __forceinline__ void async_copy16(const void* g, void* l) {
    __builtin_amdgcn_global_load_lds(
        (gu32*)(unsigned long long)g,
        (lu32*)(unsigned int)(unsigned long long)l,
        16, 0, 0);
}

// ---------------------------------------------------------------------------
// prep (merged): rows [0,BB) = x scaled by 1/var; rows [BB,BB+CC) = means.
// emit bf16 row + fp32 sum of squares. 256 thr/row, 8 elems/thread.
// ---------------------------------------------------------------------------
__global__ void prep_rows(const float* __restrict__ x,
                          const float* __restrict__ means,
                          unsigned short* __restrict__ xb,
                          unsigned short* __restrict__ mb,
                          float* __restrict__ x2,
                          float* __restrict__ m2,
                          const float* __restrict__ varp) {
    const int blk = blockIdx.x;
    const bool isx = blk < BB;
    const int row = isx ? blk : blk - BB;
    const int t = threadIdx.x;
    const float scale = isx ? (1.0f / varp[0]) : 1.0f;
    const float* in = isx ? x : means;
    unsigned short* outb = isx ? xb : mb;
    const size_t base = (size_t)row * FF + (size_t)t * 8;
    const float4 a = *(const float4*)(in + base);
    const float4 b = *(const float4*)(in + base + 4);
    float v[8] = {a.x * scale, a.y * scale, a.z * scale, a.w * scale,
                  b.x * scale, b.y * scale, b.z * scale, b.w * scale};
    float s = 0.0f;
    bf16x8 h;
#pragma unroll
    for (int i = 0; i < 8; ++i) {
        s += v[i] * v[i];
        h[i] = (__bf16)v[i];
    }
    *(bf16x8*)(outb + base) = h;
#pragma unroll
    for (int off = 32; off > 0; off >>= 1) s += __shfl_down(s, off);
    __shared__ float red[4];
    if ((t & 63) == 0) red[t >> 6] = s;
    __syncthreads();
    if (t == 0) {
        float tot = (red[0] + red[1]) + (red[2] + red[3]);
        if (isx) x2[row] = tot; else m2[row] = tot;
    }
}

// ---------------------------------------------------------------------------
// GEMM cross[b][c] = sum_f xs[b][f]*means[c][f]  (row-major, K contig: NT)
//
// 256x256 tile, 512 thr = 8 waves (2M x 4N), per-wave output 128x64 via
// 8x4 of v_mfma_f32_16x16x32_bf16.  K consumed in chunks of 32 through a
// RING of 4 LDS slots (slot = A 256x32 + B 256x32 bf16 = 32 KB; 128 KiB
// total -> 1 block/CU, grid = 256 = chip-exact).
//
// m201-style fine phases: each chunk = TWO phases.
//   even (chunk u): vmcnt(8)+barrier+schedbar | 8 af + 2 bf ds_read_b128,
//       STAGE_A(u+3) | barrier+lgkmcnt(0)+schedbar | setprio{16 MFMA j=0,1}
//   odd:            barrier+schedbar | 2 bf reads, STAGE_B(u+3)
//                 | barrier+lgkmcnt(0)+schedbar | setprio{16 MFMA j=2,3}
// Barrier density = 1 per 8k of K (same as the 1563-TF m201 template).
// Counted vmcnt only at chunk boundary, never drained in-loop (T4).
//
// Stage-point order per wave is globally sequential (A-pair then B-pair per
// chunk), so at even-phase start the 12 outstanding loads are chunks
// u..u+2; vmcnt(8) retires exactly chunk u's A+B.  Tail: 8, 8, 4, 0.
// Overwrite safety: slot (u+3)&3 was last read in chunk u-1's phases, whose
// ds_reads complete before that phase's lgkmcnt(0)+MFMA, hence before the
// phase-start barriers any wave must pass to reach the STAGE.
//
// LDS rows 64 B (4 x 16B chunks); phys chunk c' = c ^ ((row>>1)&3):
// frag reads are 2-way banked = free (m136).  Same XOR pre-applied to the
// global source (DMA dest stays linear, rule #21).
//
// Block->XCD map: XCD x (= bx&7, m09) gets bm in {4x..4x+3} x bn 0..7:
// A panels fetched once total (32 MB), B once per XCD (64 MB) — HBM ~1 TB/s
// demand, far under ceiling.
// ---------------------------------------------------------------------------
__global__ __launch_bounds__(512, 2) void gemm_epi(
    const unsigned short* __restrict__ A,   // xs  bf16 [BB][FF]
    const unsigned short* __restrict__ Bm,  // means bf16 [CC][FF]
    const float* __restrict__ x2,           // [BB]
    const float* __restrict__ m2,           // [CC]
    float* __restrict__ expo,               // [BB][CC]
    float* __restrict__ cum) {              // [BB][CC]
    __shared__ __align__(16) unsigned short As[4][256 * 32];
    __shared__ __align__(16) unsigned short Bs[4][256 * 32];

    const int t = threadIdx.x;
    const int wave = t >> 6, lane = t & 63;
    const int bx = blockIdx.x;
    const int xcd = bx & 7, q = bx >> 3;                // q = 0..31 within XCD
    const int bm = xcd * 4 + (q >> 3);                  // 0..31
    const int bn = q & 7;                               // 0..7
    const int rowA0 = bm * 256, rowB0 = bn * 256;
    const int wm = wave >> 2, wn = wave & 3;

    // staging: wave writes 16 rows x 64B linear per instruction.
    const int sr = lane >> 2;                           // 0..15
    const int sc = ((lane & 3) ^ ((sr >> 1) & 3)) * 8;  // source col (shorts)
    const unsigned short* gA0 = A  + (size_t)(rowA0 +       wave * 16 + sr) * FF + sc;
    const unsigned short* gA1 = A  + (size_t)(rowA0 + 128 + wave * 16 + sr) * FF + sc;
    const unsigned short* gB0 = Bm + (size_t)(rowB0 +       wave * 16 + sr) * FF + sc;
    const unsigned short* gB1 = Bm + (size_t)(rowB0 + 128 + wave * 16 + sr) * FF + sc;
    const int ldsOff = wave * 16 * 32;                  // shorts

    // fragment reads (mfma 16x16x32: row = lane&15, k-half = lane>>4)
    const int rl = lane & 15, kb = lane >> 4;
    const int pcol = (kb ^ ((rl >> 1) & 3)) * 8;        // phys col (shorts)
    const int arow = (wm * 128 + rl) * 32 + pcol;
    const int brow = (wn * 64  + rl) * 32 + pcol;

    f32x4 acc[8][4] = {};

    auto STAGE_A = [&](int slot, int kc) {
        const int ko = kc * 32;
        async_copy16(gA0 + ko, &As[slot][ldsOff]);
        async_copy16(gA1 + ko, &As[slot][128 * 32 + ldsOff]);
    };
    auto STAGE_B = [&](int slot, int kc) {
        const int ko = kc * 32;
        async_copy16(gB0 + ko, &Bs[slot][ldsOff]);
        async_copy16(gB1 + ko, &Bs[slot][128 * 32 + ldsOff]);
    };

    bf16x8 af[8], bf0, bf1, bf2, bf3;

    // one chunk = two m201-style phases. DO_STAGE: 0 = none, 1 = stage kc.
    auto CHUNK = [&](int slot, int nslot, int kc, int vm, bool do_stage) {
        // ---- even phase: vmcnt + barrier, A/B(j01) reads, STAGE_A, MFMA j01
        switch (vm) {  // counted wait: literal asm per value
            case 8: asm volatile("s_waitcnt vmcnt(8)" ::: "memory"); break;
            case 4: asm volatile("s_waitcnt vmcnt(4)" ::: "memory"); break;
            default: asm volatile("s_waitcnt vmcnt(0)" ::: "memory"); break;
        }
        __builtin_amdgcn_s_barrier();
        __builtin_amdgcn_sched_barrier(0);
#pragma unroll
        for (int i = 0; i < 8; ++i) af[i] = *(const bf16x8*)&As[slot][arow + i * 16 * 32];
        bf0 = *(const bf16x8*)&Bs[slot][brow + 0 * 16 * 32];
        bf1 = *(const bf16x8*)&Bs[slot][brow + 1 * 16 * 32];
        if (do_stage) STAGE_A(nslot, kc);
        __builtin_amdgcn_s_barrier();
        asm volatile("s_waitcnt lgkmcnt(0)" ::: "memory");
        __builtin_amdgcn_sched_barrier(0);
        __builtin_amdgcn_s_setprio(1);
#pragma unroll
        for (int i = 0; i < 8; ++i) {
            acc[i][0] = __builtin_amdgcn_mfma_f32_16x16x32_bf16(af[i], bf0, acc[i][0], 0, 0, 0);
            acc[i][1] = __builtin_amdgcn_mfma_f32_16x16x32_bf16(af[i], bf1, acc[i][1], 0, 0, 0);
        }
        __builtin_amdgcn_s_setprio(0);
        // ---- odd phase: B(j23) reads, STAGE_B, MFMA j23
        __builtin_amdgcn_s_barrier();
        __builtin_amdgcn_sched_barrier(0);
        bf2 = *(const bf16x8*)&Bs[slot][brow + 2 * 16 * 32];
        bf3 = *(const bf16x8*)&Bs[slot][brow + 3 * 16 * 32];
        if (do_stage) STAGE_B(nslot, kc);
        __builtin_amdgcn_s_barrier();
        asm volatile("s_waitcnt lgkmcnt(0)" ::: "memory");
        __builtin_amdgcn_sched_barrier(0);
        __builtin_amdgcn_s_setprio(1);
#pragma unroll
        for (int i = 0; i < 8; ++i) {
            acc[i][2] = __builtin_amdgcn_mfma_f32_16x16x32_bf16(af[i], bf2, acc[i][2], 0, 0, 0);
            acc[i][3] = __builtin_amdgcn_mfma_f32_16x16x32_bf16(af[i], bf3, acc[i][3], 0, 0, 0);
        }
        __builtin_amdgcn_s_setprio(0);
    };

    // prologue: 3 chunks in flight (12 loads), order A,B per chunk
    STAGE_A(0, 0); STAGE_B(0, 0);
    STAGE_A(1, 1); STAGE_B(1, 1);
    STAGE_A(2, 2); STAGE_B(2, 2);

    // chunks 0..59 stage chunks 3..62; chunk 60 stages 63; 61..63 drain.
#pragma unroll 4
    for (int u = 0; u < 60; ++u)
        CHUNK(u & 3, (u + 3) & 3, u + 3, 8, true);
    CHUNK(0, 3, 63, 8, true);    // chunk 60
    CHUNK(1, 0, 0, 8, false);    // chunk 61
    CHUNK(2, 0, 0, 4, false);    // chunk 62
    CHUNK(3, 0, 0, 0, false);    // chunk 63

    // epilogue: C/D layout col = lane&15, row = (lane>>4)*4 + reg  [m89/m91]
    const int ln = lane & 15, lq = lane >> 4;
    const int grow0 = rowA0 + wm * 128 + lq * 4;
    const int gcol0 = rowB0 + wn * 64 + ln;
    float m2v[4];
#pragma unroll
    for (int j = 0; j < 4; ++j) m2v[j] = m2[gcol0 + j * 16];

#pragma unroll
    for (int i = 0; i < 8; ++i) {
        float x2r[4];
#pragma unroll
        for (int r = 0; r < 4; ++r) x2r[r] = x2[grow0 + i * 16 + r];
#pragma unroll
        for (int j = 0; j < 4; ++j)
#pragma unroll
            for (int r = 0; r < 4; ++r) {
                const float d2 = x2r[r] + m2v[j] - 2.0f * acc[i][j][r];
                const float d = sqrtf(fmaxf(d2, 0.0f));
                const size_t idx = (size_t)(grow0 + i * 16 + r) * CC + (gcol0 + j * 16);
                __builtin_nontemporal_store(d, &cum[idx]);  // never re-read
                expo[idx] = -d;                              // re-read by softmax
            }
    }
}

// ---------------------------------------------------------------------------
// softmax over each row of exponent -> probs. one block (256 thr) per row.
// No max-subtraction: d = sqrt(x2+m2-2c) <= sqrt(~4500) < 68, so
// exp(-d) >= 3e-30 >> FLT_MIN — unshifted exp is safe and exact enough.
// ---------------------------------------------------------------------------
__global__ void softmax_rows(const float* __restrict__ e, float* __restrict__ p) {
    const int row = blockIdx.x;
    const int t = threadIdx.x;
    const size_t base = (size_t)row * CC + (size_t)t * 8;
    const float4 a = *(const float4*)(e + base);
    const float4 b = *(const float4*)(e + base + 4);
    float ev[8] = {__expf(a.x), __expf(a.y), __expf(a.z), __expf(a.w),
                   __expf(b.x), __expf(b.y), __expf(b.z), __expf(b.w)};
    float s = 0.0f;
#pragma unroll
    for (int i = 0; i < 8; ++i) s += ev[i];
#pragma unroll
    for (int off = 32; off > 0; off >>= 1) s += __shfl_down(s, off);
    __shared__ float reds[4];
    if ((t & 63) == 0) reds[t >> 6] = s;
    __syncthreads();
    s = (reds[0] + reds[1]) + (reds[2] + reds[3]);
    const float inv = 1.0f / s;

    f32x4 o0 = {ev[0] * inv, ev[1] * inv, ev[2] * inv, ev[3] * inv};
    f32x4 o1 = {ev[4] * inv, ev[5] * inv, ev[6] * inv, ev[7] * inv};
    __builtin_nontemporal_store(o0, (f32x4*)(p + base));
    __builtin_nontemporal_store(o1, (f32x4*)(p + base + 4));
}

// ---------------------------------------------------------------------------
extern "C" void kernel_launch(void* const* d_in, const int* in_sizes, int n_in,
                              void* d_out, int out_size, void* d_ws, size_t ws_size,
                              hipStream_t stream) {
    const float* x     = (const float*)d_in[0];   // [BB][FF]
    const float* means = (const float*)d_in[1];   // [CC][FF]
    const float* var   = (const float*)d_in[2];   // [1]
    float* out = (float*)d_out;

    // workspace layout: xb bf16 [BB*FF] | mb bf16 [CC*FF] | x2 f32[BB] | m2 f32[CC]
    unsigned short* xb = (unsigned short*)d_ws;
    unsigned short* mb = xb + (size_t)BB * FF;
    float* x2 = (float*)(mb + (size_t)CC * FF);
    float* m2 = x2 + BB;

    float* probs = out;                          // output 0
    float* expo  = out + (size_t)BB * CC;        // output 1
    float* cum   = expo + (size_t)BB * CC;       // output 2

    prep_rows<<<BB + CC, 256, 0, stream>>>(x, means, xb, mb, x2, m2, var);
    gemm_epi<<<(BB / 256) * (CC / 256), 512, 0, stream>>>(xb, mb, x2, m2, expo, cum);
    softmax_rows<<<BB, 256, 0, stream>>>(expo, probs);
}